// Round 8
// baseline (198.840 us; speedup 1.0000x reference)
//
#include <hip/hip_runtime.h>
#include <hip/hip_bf16.h>

// SpikingSelfAttention — round 8: MFMA attention tail.
// k_attn: O^T = (M1+M2)^T ⊗ Q via MFMA, M split into two exact bf16 planes
// (M integer <=1024: M1=RNE(M), M2=RNE(M-M1), residual integer <=2 — exact).
// k_kvM: 8 L-chunks (512 blocks) for 2 blocks/CU.
// GEMM kernels (k_qkv/k_out) unchanged from round 7.

#define NB 8
#define NC 512
#define NT 4
#define NN 256
#define NL 1024
#define NH 8
#define ND 64
#define BCL (NB*NC*NL)

typedef __attribute__((ext_vector_type(8))) short  short8v;
typedef __attribute__((ext_vector_type(8))) unsigned short us8;
typedef __attribute__((ext_vector_type(4))) unsigned short us4;
typedef __attribute__((ext_vector_type(4))) float f32x4;

__device__ __forceinline__ float bu2f(unsigned short u) {
  return __uint_as_float(((unsigned)u) << 16);
}
__device__ __forceinline__ unsigned short f2bu(float f) {   // RNE f32->bf16
  unsigned b = __float_as_uint(f);
  return (unsigned short)((b + 0x7FFFu + ((b >> 16) & 1u)) >> 16);
}

// ---------------------------------------------------------------------------
// k_prep: blocks [0,512) = weight split into fragment-ordered H2;
//         blocks [512,1024) = proj BN+LIF -> ST0[b][l][c] bf16.
// H2 layout: offset = ((((p*3+j)*4+rt)*8+k0i)*8+chunk)*1024 + r*8
__global__ void k_prep(const float* __restrict__ wq, const float* __restrict__ wk,
                       const float* __restrict__ wv, const float* __restrict__ wp,
                       const float* __restrict__ x,
                       const float* __restrict__ g,  const float* __restrict__ bt,
                       const float* __restrict__ mu, const float* __restrict__ var,
                       unsigned short* __restrict__ H2,
                       unsigned short* __restrict__ ST0) {
  if (blockIdx.x < 512) {
    int gi = blockIdx.x * 256 + threadIdx.x;       // (p,o,k8): 4*512*64
    int p = gi >> 15;
    int o = (gi >> 6) & 511;
    int k8 = gi & 63;
    int rt = o >> 7, r = o & 127;
    int k0i = k8 >> 3, chunk = k8 & 7;
    const float* W = (p == 0) ? wq : (p == 1) ? wk : (p == 2) ? wv : wp;
    const float* src = W + (size_t)o * NC + k8 * 8;
    us8 a[3];
#pragma unroll
    for (int i = 0; i < 8; i++) {
      float w = src[i];
      unsigned short u1 = f2bu(w);
      float r1 = w - bu2f(u1);
      unsigned short u2 = f2bu(r1);
      float r2 = r1 - bu2f(u2);
      unsigned short u3 = f2bu(r2);
      a[0][i] = u1; a[1][i] = u2; a[2][i] = u3;
    }
#pragma unroll
    for (int j = 0; j < 3; j++) {
      size_t off = ((size_t)((((p * 3 + j) * 4 + rt) * 8 + k0i) * 8 + chunk)) * 1024
                   + (size_t)r * 8;
      *(us8*)&H2[off] = a[j];
    }
  } else {
    int bidx = blockIdx.x - 512;
    int b  = bidx >> 6;
    int c0 = (bidx & 63) * 8;
    int n  = threadIdx.x;
    unsigned short spk[NT][8];
#pragma unroll
    for (int i = 0; i < 8; i++) {
      int c = c0 + i;
      float inv = g[c] / sqrtf(var[c] + 1e-5f);
      float m = mu[c], be = bt[c];
      const float* xp = x + ((size_t)(b * NC + c)) * NL + n;
      float v = 0.f;
#pragma unroll
      for (int t = 0; t < NT; t++) {
        float y = (xp[t * NN] - m) * inv + be;
        v = v + (y - v) / 1.5f;
        unsigned short s = 0;
        if (v - 1.0f >= 0.f) { s = 0x3F80; v = 0.f; }
        spk[t][i] = s;
      }
    }
#pragma unroll
    for (int t = 0; t < NT; t++) {
      us8 pk;
#pragma unroll
      for (int i = 0; i < 8; i++) pk[i] = spk[t][i];
      *(us8*)&ST0[((size_t)b * NL + t * NN + n) * NC + c0] = pk;
    }
  }
}

// ---------------------------------------------------------------------------
// Fused q/k/v projection + BN + LIF (round-7 structure, unchanged).
__global__ __launch_bounds__(256) void
k_qkv(const unsigned short* __restrict__ H2,
      const unsigned short* __restrict__ ST0,
      const float* __restrict__ gq, const float* __restrict__ bq,
      const float* __restrict__ mq, const float* __restrict__ vq,
      const float* __restrict__ gk, const float* __restrict__ bk,
      const float* __restrict__ mk, const float* __restrict__ vk,
      const float* __restrict__ gv, const float* __restrict__ bv,
      const float* __restrict__ mv, const float* __restrict__ vv,
      unsigned short* __restrict__ STq, unsigned short* __restrict__ STk,
      unsigned short* __restrict__ STv) {
  __shared__ __align__(16) unsigned short sB[2][128 * 64];

  int id = blockIdx.x;                  // 768 = 8 n0 * 4 rt * 8 b * 3 p
  int n0 = (id & 7) * 32;
  int rt = (id >> 3) & 3;
  int b  = (id >> 5) & 7;
  int p  = id >> 8;

  int tid = threadIdx.x;
  int w = tid >> 6, lane = tid & 63, quad = lane >> 4, l15 = lane & 15;
  int xorv = l15 & 7;

  const unsigned short* Sb = ST0 + (size_t)b * NL * NC;

  f32x4 acc[2][8];
#pragma unroll
  for (int ri = 0; ri < 2; ri++)
#pragma unroll
    for (int jj = 0; jj < 8; jj++) acc[ri][jj] = (f32x4){0.f, 0.f, 0.f, 0.f};

  us8 breg[4];
  int ccs[4], segs[4];
  size_t bsrc[4];
#pragma unroll
  for (int i = 0; i < 4; i++) {
    int idx = tid + i * 256;
    int cc = idx >> 3, seg = idx & 7;
    int t = (cc >> 4) & 3, nn = (cc & 15) | ((cc >> 6) << 4);
    ccs[i] = cc; segs[i] = seg;
    bsrc[i] = (size_t)(t * NN + n0 + nn) * NC + seg * 8;
  }
#pragma unroll
  for (int i = 0; i < 4; i++) breg[i] = *(const us8*)&Sb[bsrc[i]];      // k0=0
#pragma unroll
  for (int i = 0; i < 4; i++)
    *(us8*)&sB[0][ccs[i] * 64 + ((segs[i] ^ (ccs[i] & 7)) << 3)] = breg[i];

  for (int k0i = 0; k0i < 8; k0i++) {
    __syncthreads();
    int buf = k0i & 1;
    if (k0i < 7) {
#pragma unroll
      for (int i = 0; i < 4; i++)
        breg[i] = *(const us8*)&Sb[bsrc[i] + (size_t)(k0i + 1) * 64];
    }
#pragma unroll
    for (int ks = 0; ks < 2; ks++) {
      int c8 = ks * 4 + quad;
      int poff = (c8 ^ xorv) << 3;
      short8v bf[8];
#pragma unroll
      for (int jj = 0; jj < 8; jj++)
        bf[jj] = *(const short8v*)&sB[buf][(jj * 16 + l15) * 64 + poff];
#pragma unroll
      for (int j = 0; j < 3; j++) {
        const unsigned short* Hj =
            H2 + ((size_t)(((p * 3 + j) * 4 + rt) * 8 + k0i)) * 8192
               + (size_t)c8 * 1024;
        short8v a0 = *(const short8v*)&Hj[(w * 32 + l15) * 8];
        short8v a1 = *(const short8v*)&Hj[(w * 32 + 16 + l15) * 8];
#pragma unroll
        for (int jj = 0; jj < 8; jj++) {
          acc[0][jj] = __builtin_amdgcn_mfma_f32_16x16x32_bf16(a0, bf[jj], acc[0][jj], 0, 0, 0);
          acc[1][jj] = __builtin_amdgcn_mfma_f32_16x16x32_bf16(a1, bf[jj], acc[1][jj], 0, 0, 0);
        }
      }
    }
    if (k0i < 7) {
#pragma unroll
      for (int i = 0; i < 4; i++)
        *(us8*)&sB[buf ^ 1][ccs[i] * 64 + ((segs[i] ^ (ccs[i] & 7)) << 3)] = breg[i];
    }
  }

  const float *g, *bb, *mm, *vr;
  unsigned short* So;
  if (p == 0)      { g = gq; bb = bq; mm = mq; vr = vq; So = STq; }
  else if (p == 1) { g = gk; bb = bk; mm = mk; vr = vk; So = STk; }
  else             { g = gv; bb = bv; mm = mv; vr = vv; So = STv; }
  So += (size_t)b * NL * NC;

#pragma unroll
  for (int ri = 0; ri < 2; ri++) {
    int ob = rt * 128 + w * 32 + ri * 16 + quad * 4;
    float av[4], mvv[4], bvv[4];
#pragma unroll
    for (int r = 0; r < 4; r++) {
      av[r]  = g[ob + r] / sqrtf(vr[ob + r] + 1e-5f);
      mvv[r] = mm[ob + r];
      bvv[r] = bb[ob + r];
    }
#pragma unroll
    for (int nh = 0; nh < 2; nh++) {
      int n = n0 + (nh << 4) + l15;
      unsigned short sp[4][4];          // [t][r]
#pragma unroll
      for (int r = 0; r < 4; r++) {
        float vmem = 0.f;
#pragma unroll
        for (int t = 0; t < NT; t++) {
          float y = (acc[ri][nh * 4 + t][r] - mvv[r]) * av[r] + bvv[r];
          vmem = vmem + (y - vmem) / 1.5f;
          unsigned short s = 0;
          if (vmem - 1.0f >= 0.f) { s = 0x3F80; vmem = 0.f; }
          sp[t][r] = s;
        }
      }
#pragma unroll
      for (int t = 0; t < NT; t++) {
        us4 pk;
#pragma unroll
        for (int r = 0; r < 4; r++) pk[r] = sp[t][r];
        *(us4*)&So[(size_t)(t * NN + n) * NC + ob] = pk;
      }
    }
  }
}

// ---------------------------------------------------------------------------
// Partial Gram: Mpart[ch][bh][e][dd] = sum_{l in 128-chunk} K[l][e]*V[l][dd].
// 512 blocks (2/CU). Integer-exact partials.
__global__ void k_kvM(const unsigned short* __restrict__ STk,
                      const unsigned short* __restrict__ STv,
                      float* __restrict__ Mpart) {
  int bh = blockIdx.x, ch = blockIdx.y;       // ch 0..7
  int b = bh >> 3, h = bh & 7;
  const unsigned short* Kp = STk + (size_t)b * NL * NC + h * ND;
  const unsigned short* Vp = STv + (size_t)b * NL * NC + h * ND;
  __shared__ float sK[64][72];
  __shared__ float sV[64][72];
  int tid = threadIdx.x, tx = tid & 15, ty = tid >> 4;
  float acc[4][4] = {};
  for (int lt = 0; lt < 2; lt++) {
    int lb = ch * 128 + lt * 64;
#pragma unroll
    for (int i = 0; i < 2; i++) {
      int idx = tid + i * 256;
      int r = idx >> 3, seg = idx & 7;
      us8 kv = *(const us8*)&Kp[(size_t)(lb + r) * NC + seg * 8];
      us8 vv = *(const us8*)&Vp[(size_t)(lb + r) * NC + seg * 8];
#pragma unroll
      for (int q2 = 0; q2 < 8; q2++) {
        sK[r][seg * 8 + q2] = bu2f(kv[q2]);
        sV[r][seg * 8 + q2] = bu2f(vv[q2]);
      }
    }
    __syncthreads();
#pragma unroll 8
    for (int lc = 0; lc < 64; lc++) {
      float kvx[4], vvx[4];
#pragma unroll
      for (int i = 0; i < 4; i++) kvx[i] = sK[lc][ty * 4 + i];
#pragma unroll
      for (int j2 = 0; j2 < 4; j2++) vvx[j2] = sV[lc][tx * 4 + j2];
#pragma unroll
      for (int i = 0; i < 4; i++)
#pragma unroll
        for (int j2 = 0; j2 < 4; j2++)
          acc[i][j2] += kvx[i] * vvx[j2];
    }
    __syncthreads();
  }
  float* Mp = Mpart + ((size_t)ch * 64 + bh) * 4096;
#pragma unroll
  for (int i = 0; i < 4; i++) {
    float4 v4 = make_float4(acc[i][0], acc[i][1], acc[i][2], acc[i][3]);
    *(float4*)&Mp[(ty * 4 + i) * ND + tx * 4] = v4;
  }
}

// ---------------------------------------------------------------------------
// MFMA attention: O^T[dd][l] = sum_e (M1+M2)^T[dd][e] * Q[l][e]; spike O>=12.
// A = M^T planes (LDS, XOR-swizzled); B = Q natural [l][c] (direct global).
// Grid (4 lt, 64 bh); wave w covers 64 l.
__global__ __launch_bounds__(256) void
k_attn(const unsigned short* __restrict__ STq,
       const float* __restrict__ Mpart,
       unsigned short* __restrict__ STs) {
  __shared__ unsigned short MT1[64 * 64];   // [dd][e], 16B chunks phys = c ^ (dd&7)
  __shared__ unsigned short MT2[64 * 64];
  int lt = blockIdx.x, bh = blockIdx.y;
  int b = bh >> 3, h = bh & 7;
  int tid = threadIdx.x;
  int w = tid >> 6, lane = tid & 63, quad = lane >> 4, l15 = lane & 15;

  // Prologue: sum 8 chunks (float4 reads), exact 2-plane bf16 split, store M^T.
#pragma unroll
  for (int i = 0; i < 4; i++) {
    int idx4 = tid + i * 256;                // float4 index; idx = idx4*4
    float4 s = ((const float4*)Mpart)[(size_t)bh * 1024 + idx4];
#pragma unroll
    for (int ch = 1; ch < 8; ch++) {
      float4 t = ((const float4*)Mpart)[((size_t)ch * 64 + bh) * 1024 + idx4];
      s.x += t.x; s.y += t.y; s.z += t.z; s.w += t.w;
    }
    int e = idx4 >> 4;                       // idx4*4 >> 6
    int dd0 = (idx4 * 4) & 63;
    int chunk = e >> 3;
    float sv[4] = {s.x, s.y, s.z, s.w};
#pragma unroll
    for (int r = 0; r < 4; r++) {
      int dd = dd0 + r;
      unsigned short u1 = f2bu(sv[r]);
      unsigned short u2 = f2bu(sv[r] - bu2f(u1));
      int pos = dd * 64 + (((chunk ^ (dd & 7)) << 3) | (e & 7));
      MT1[pos] = u1;
      MT2[pos] = u2;
    }
  }
  __syncthreads();

  const unsigned short* Qp = STq + (size_t)b * NL * NC + h * ND;
  int lbase = lt * 256 + w * 64;

  f32x4 acc[4][4];                           // [ddtile][ltile]
#pragma unroll
  for (int dt = 0; dt < 4; dt++)
#pragma unroll
    for (int j = 0; j < 4; j++) acc[dt][j] = (f32x4){0.f, 0.f, 0.f, 0.f};

#pragma unroll
  for (int ks = 0; ks < 2; ks++) {
    short8v bq[4];
#pragma unroll
    for (int ltile = 0; ltile < 4; ltile++)
      bq[ltile] = *(const short8v*)&Qp[(size_t)(lbase + ltile * 16 + l15) * NC
                                       + ks * 32 + quad * 8];
    int c8 = ks * 4 + quad;
#pragma unroll
    for (int dt = 0; dt < 4; dt++) {
      int dd = dt * 16 + l15;
      int off = dd * 64 + ((c8 ^ (dd & 7)) << 3);
      short8v a1 = *(const short8v*)&MT1[off];
      short8v a2 = *(const short8v*)&MT2[off];
#pragma unroll
      for (int ltile = 0; ltile < 4; ltile++) {
        acc[dt][ltile] = __builtin_amdgcn_mfma_f32_16x16x32_bf16(a1, bq[ltile], acc[dt][ltile], 0, 0, 0);
        acc[dt][ltile] = __builtin_amdgcn_mfma_f32_16x16x32_bf16(a2, bq[ltile], acc[dt][ltile], 0, 0, 0);
      }
    }
  }

  unsigned short* Sp = STs + (size_t)b * NL * NC + h * ND;
#pragma unroll
  for (int dt = 0; dt < 4; dt++)
#pragma unroll
    for (int ltile = 0; ltile < 4; ltile++) {
      int l = lbase + ltile * 16 + l15;
      int dd = dt * 16 + quad * 4;
      us4 pk;
#pragma unroll
      for (int r = 0; r < 4; r++) pk[r] = (acc[dt][ltile][r] >= 12.0f) ? 0x3F80 : 0;
      *(us4*)&Sp[(size_t)l * NC + dd] = pk;
    }
}

// ---------------------------------------------------------------------------
// Final projection (round-7 structure, unchanged).
__global__ __launch_bounds__(256) void
k_out(const unsigned short* __restrict__ H2,
      const unsigned short* __restrict__ STs,
      const float* __restrict__ bp, float* __restrict__ out) {
  __shared__ __align__(16) unsigned short sB[2][64 * 64];

  int id = blockIdx.x;                  // 512 = 16 l0 * 4 rt * 8 b
  int l0 = (id & 15) * 64;
  int rt = (id >> 4) & 3;
  int b  = id >> 6;

  int tid = threadIdx.x;
  int w = tid >> 6, lane = tid & 63, quad = lane >> 4, l15 = lane & 15;
  int xorv = l15 & 7;

  const unsigned short* Sb = STs + (size_t)b * NL * NC;

  f32x4 acc[2][4];
#pragma unroll
  for (int ri = 0; ri < 2; ri++)
#pragma unroll
    for (int jj = 0; jj < 4; jj++) acc[ri][jj] = (f32x4){0.f, 0.f, 0.f, 0.f};

  us8 breg[2];
  int ccs[2], segs[2];
  size_t bsrc[2];
#pragma unroll
  for (int i = 0; i < 2; i++) {
    int idx = tid + i * 256;
    int cc = idx >> 3, seg = idx & 7;
    ccs[i] = cc; segs[i] = seg;
    bsrc[i] = (size_t)(l0 + cc) * NC + seg * 8;
  }
#pragma unroll
  for (int i = 0; i < 2; i++) breg[i] = *(const us8*)&Sb[bsrc[i]];
#pragma unroll
  for (int i = 0; i < 2; i++)
    *(us8*)&sB[0][ccs[i] * 64 + ((segs[i] ^ (ccs[i] & 7)) << 3)] = breg[i];

  for (int k0i = 0; k0i < 8; k0i++) {
    __syncthreads();
    int buf = k0i & 1;
    if (k0i < 7) {
#pragma unroll
      for (int i = 0; i < 2; i++)
        breg[i] = *(const us8*)&Sb[bsrc[i] + (size_t)(k0i + 1) * 64];
    }
#pragma unroll
    for (int ks = 0; ks < 2; ks++) {
      int c8 = ks * 4 + quad;
      int poff = (c8 ^ xorv) << 3;
      short8v bf[4];
#pragma unroll
      for (int jj = 0; jj < 4; jj++)
        bf[jj] = *(const short8v*)&sB[buf][(jj * 16 + l15) * 64 + poff];
#pragma unroll
      for (int j = 0; j < 3; j++) {
        const unsigned short* Hj =
            H2 + ((size_t)(((9 + j) * 4 + rt) * 8 + k0i)) * 8192   // p=3
               + (size_t)c8 * 1024;
        short8v a0 = *(const short8v*)&Hj[(w * 32 + l15) * 8];
        short8v a1 = *(const short8v*)&Hj[(w * 32 + 16 + l15) * 8];
#pragma unroll
        for (int jj = 0; jj < 4; jj++) {
          acc[0][jj] = __builtin_amdgcn_mfma_f32_16x16x32_bf16(a0, bf[jj], acc[0][jj], 0, 0, 0);
          acc[1][jj] = __builtin_amdgcn_mfma_f32_16x16x32_bf16(a1, bf[jj], acc[1][jj], 0, 0, 0);
        }
      }
    }
    if (k0i < 7) {
#pragma unroll
      for (int i = 0; i < 2; i++)
        *(us8*)&sB[buf ^ 1][ccs[i] * 64 + ((segs[i] ^ (ccs[i] & 7)) << 3)] = breg[i];
    }
  }

#pragma unroll
  for (int ri = 0; ri < 2; ri++) {
    int ob = rt * 128 + w * 32 + ri * 16 + quad * 4;
#pragma unroll
    for (int jj = 0; jj < 4; jj++) {
      int l = l0 + jj * 16 + l15;
#pragma unroll
      for (int r = 0; r < 4; r++)
        out[((size_t)(b * NC + ob + r)) * NL + l] = acc[ri][jj][r] + bp[ob + r];
    }
  }
}

// ---------------------------------------------------------------------------
extern "C" void kernel_launch(void* const* d_in, const int* in_sizes, int n_in,
                              void* d_out, int out_size, void* d_ws, size_t ws_size,
                              hipStream_t stream) {
  (void)in_sizes; (void)n_in; (void)out_size; (void)ws_size;
  const float* x   = (const float*)d_in[0];
  const float* wq  = (const float*)d_in[1];
  const float* wk  = (const float*)d_in[2];
  const float* wv  = (const float*)d_in[3];
  const float* wp  = (const float*)d_in[4];
  const float* bp  = (const float*)d_in[5];
  const float* gq  = (const float*)d_in[6];
  const float* bq  = (const float*)d_in[7];
  const float* mq  = (const float*)d_in[8];
  const float* vq  = (const float*)d_in[9];
  const float* gk  = (const float*)d_in[10];
  const float* bk  = (const float*)d_in[11];
  const float* mk  = (const float*)d_in[12];
  const float* vk  = (const float*)d_in[13];
  const float* gv  = (const float*)d_in[14];
  const float* bv  = (const float*)d_in[15];
  const float* mv  = (const float*)d_in[16];
  const float* vvv = (const float*)d_in[17];
  const float* gp  = (const float*)d_in[18];
  const float* bpn = (const float*)d_in[19];
  const float* mp  = (const float*)d_in[20];
  const float* vp  = (const float*)d_in[21];

  unsigned short* H2  = (unsigned short*)d_ws;
  unsigned short* ST0 = H2 + (size_t)4 * 3 * NC * NC;
  unsigned short* STq = ST0 + BCL;
  unsigned short* STk = STq + BCL;
  unsigned short* STv = STk + BCL;
  unsigned short* STs = STv + BCL;
  float* Mpart = (float*)(STs + BCL);

  dim3 blk(256);
  k_prep<<<1024, blk, 0, stream>>>(wq, wk, wv, wp, x, gp, bpn, mp, vp, H2, ST0);
  k_qkv<<<768, blk, 0, stream>>>(H2, ST0,
      gq, bq, mq, vq, gk, bk, mk, vk, gv, bv, mv, vvv, STq, STk, STv);
  k_kvM<<<dim3(64, 8), blk, 0, stream>>>(STk, STv, Mpart);
  k_attn<<<dim3(4, 64), blk, 0, stream>>>(STq, Mpart, STs);
  k_out<<<512, blk, 0, stream>>>(H2, STs, bp, (float*)d_out);
}

// Round 9
// 197.509 us; speedup vs baseline: 1.0067x; 1.0067x over previous
//
#include <hip/hip_runtime.h>
#include <hip/hip_bf16.h>

// SpikingSelfAttention — round 9: 32x32x16 MFMA for weight GEMMs (higher
// FLOP/cyc ceiling, half the instruction count), fragment-ordered weights for
// the 32x32 A layout. k_kvM/k_attn unchanged from round 8.
// B=8, C=512, T=4, N=256, L=1024, H=8, d=64.
// Exact 3-way bf16 weight split; binary spikes; o = q @ (k^T v) integer-exact.

#define NB 8
#define NC 512
#define NT 4
#define NN 256
#define NL 1024
#define NH 8
#define ND 64
#define BCL (NB*NC*NL)

typedef __attribute__((ext_vector_type(8))) short  short8v;
typedef __attribute__((ext_vector_type(8))) unsigned short us8;
typedef __attribute__((ext_vector_type(4))) unsigned short us4;
typedef __attribute__((ext_vector_type(4))) float f32x4;
typedef __attribute__((ext_vector_type(16))) float f32x16;

__device__ __forceinline__ float bu2f(unsigned short u) {
  return __uint_as_float(((unsigned)u) << 16);
}
__device__ __forceinline__ unsigned short f2bu(float f) {   // RNE f32->bf16
  unsigned b = __float_as_uint(f);
  return (unsigned short)((b + 0x7FFFu + ((b >> 16) & 1u)) >> 16);
}

// ---------------------------------------------------------------------------
// k_prep: blocks [0,512) = weight split into 32x32-fragment-ordered H3;
//         blocks [512,1024) = proj BN+LIF -> ST0[b][l][c] bf16.
// H3 layout: off = ((((p*3+j)*16 + rt32)*8 + k0i)*4 + kstep)*512 + lane*8
//   lane = khalf*32 + (row&31); covers A-frag of 32x32x16 directly.
__global__ void k_prep(const float* __restrict__ wq, const float* __restrict__ wk,
                       const float* __restrict__ wv, const float* __restrict__ wp,
                       const float* __restrict__ x,
                       const float* __restrict__ g,  const float* __restrict__ bt,
                       const float* __restrict__ mu, const float* __restrict__ var,
                       unsigned short* __restrict__ H3,
                       unsigned short* __restrict__ ST0) {
  if (blockIdx.x < 512) {
    int gi = blockIdx.x * 256 + threadIdx.x;       // (p,o,k8): 4*512*64
    int p = gi >> 15;
    int o = (gi >> 6) & 511;
    int k8 = gi & 63;
    int rt32 = o >> 5, lrow = o & 31;
    int k0i = k8 >> 3, kk = k8 & 7;
    int kstep = kk >> 1, khalf = kk & 1;
    int ln = khalf * 32 + lrow;
    const float* W = (p == 0) ? wq : (p == 1) ? wk : (p == 2) ? wv : wp;
    const float* src = W + (size_t)o * NC + k8 * 8;
    us8 a[3];
#pragma unroll
    for (int i = 0; i < 8; i++) {
      float w = src[i];
      unsigned short u1 = f2bu(w);
      float r1 = w - bu2f(u1);
      unsigned short u2 = f2bu(r1);
      float r2 = r1 - bu2f(u2);
      unsigned short u3 = f2bu(r2);
      a[0][i] = u1; a[1][i] = u2; a[2][i] = u3;
    }
#pragma unroll
    for (int j = 0; j < 3; j++) {
      size_t off = ((size_t)((((p * 3 + j) * 16 + rt32) * 8 + k0i) * 4 + kstep)) * 512
                   + (size_t)ln * 8;
      *(us8*)&H3[off] = a[j];
    }
  } else {
    int bidx = blockIdx.x - 512;
    int b  = bidx >> 6;
    int c0 = (bidx & 63) * 8;
    int n  = threadIdx.x;
    unsigned short spk[NT][8];
#pragma unroll
    for (int i = 0; i < 8; i++) {
      int c = c0 + i;
      float inv = g[c] / sqrtf(var[c] + 1e-5f);
      float m = mu[c], be = bt[c];
      const float* xp = x + ((size_t)(b * NC + c)) * NL + n;
      float v = 0.f;
#pragma unroll
      for (int t = 0; t < NT; t++) {
        float y = (xp[t * NN] - m) * inv + be;
        v = v + (y - v) / 1.5f;
        unsigned short s = 0;
        if (v - 1.0f >= 0.f) { s = 0x3F80; v = 0.f; }
        spk[t][i] = s;
      }
    }
#pragma unroll
    for (int t = 0; t < NT; t++) {
      us8 pk;
#pragma unroll
      for (int i = 0; i < 8; i++) pk[i] = spk[t][i];
      *(us8*)&ST0[((size_t)b * NL + t * NN + n) * NC + c0] = pk;
    }
  }
}

// ---------------------------------------------------------------------------
// Fused q/k/v projection + BN + LIF. 32x32x16 MFMA. Block tile 128 rows x
// 128 cols (32 n x 4 t); wave w owns 32-row strip x 128 cols (4 col-tiles=t).
// A-frags direct from H3 (global/L2, 1KB/wave contiguous); B in LDS dbuf,
// XOR-swizzled, 1 barrier per k0. cc = t*32 + n; col tile index == t.
__global__ __launch_bounds__(256) void
k_qkv(const unsigned short* __restrict__ H3,
      const unsigned short* __restrict__ ST0,
      const float* __restrict__ gq, const float* __restrict__ bq,
      const float* __restrict__ mq, const float* __restrict__ vq,
      const float* __restrict__ gk, const float* __restrict__ bk,
      const float* __restrict__ mk, const float* __restrict__ vk,
      const float* __restrict__ gv, const float* __restrict__ bv,
      const float* __restrict__ mv, const float* __restrict__ vv,
      unsigned short* __restrict__ STq, unsigned short* __restrict__ STk,
      unsigned short* __restrict__ STv) {
  __shared__ __align__(16) unsigned short sB[2][128 * 64];

  int id = blockIdx.x;                  // 768 = 8 n0 * 4 rt * 8 b * 3 p
  int n0 = (id & 7) * 32;
  int rt = (id >> 3) & 3;
  int b  = (id >> 5) & 7;
  int p  = id >> 8;

  int tid = threadIdx.x;
  int w = tid >> 6, lane = tid & 63;
  int l31 = lane & 31, h = lane >> 5;

  const unsigned short* Sb = ST0 + (size_t)b * NL * NC;

  f32x16 acc[4];
#pragma unroll
  for (int t4 = 0; t4 < 4; t4++)
#pragma unroll
    for (int r = 0; r < 16; r++) acc[t4][r] = 0.f;

  // B staging: 128 cc x 64 k per k0 (16 KB). 4 us8/thread.
  us8 breg[4];
  int ccs[4], segs[4];
  size_t bsrc[4];
#pragma unroll
  for (int i = 0; i < 4; i++) {
    int idx = tid + i * 256;
    int cc = idx >> 3, seg = idx & 7;
    int t = cc >> 5, nn = cc & 31;
    ccs[i] = cc; segs[i] = seg;
    bsrc[i] = (size_t)(t * NN + n0 + nn) * NC + seg * 8;
  }
#pragma unroll
  for (int i = 0; i < 4; i++) breg[i] = *(const us8*)&Sb[bsrc[i]];      // k0=0
#pragma unroll
  for (int i = 0; i < 4; i++)
    *(us8*)&sB[0][ccs[i] * 64 + ((segs[i] ^ (ccs[i] & 7)) << 3)] = breg[i];

  for (int k0i = 0; k0i < 8; k0i++) {
    __syncthreads();
    int buf = k0i & 1;
    if (k0i < 7) {
#pragma unroll
      for (int i = 0; i < 4; i++)
        breg[i] = *(const us8*)&Sb[bsrc[i] + (size_t)(k0i + 1) * 64];
    }
#pragma unroll
    for (int kstep = 0; kstep < 4; kstep++) {
      int c8 = kstep * 2 + h;
      short8v bf[4];
#pragma unroll
      for (int t4 = 0; t4 < 4; t4++) {
        int cc = t4 * 32 + l31;
        bf[t4] = *(const short8v*)&sB[buf][cc * 64 + ((c8 ^ (cc & 7)) << 3)];
      }
#pragma unroll
      for (int j = 0; j < 3; j++) {
        const unsigned short* Hj =
            H3 + ((size_t)((((p * 3 + j) * 16 + rt * 4 + w) * 8 + k0i) * 4 + kstep)) * 512;
        short8v a = *(const short8v*)&Hj[lane * 8];
#pragma unroll
        for (int t4 = 0; t4 < 4; t4++)
          acc[t4] = __builtin_amdgcn_mfma_f32_32x32x16_bf16(a, bf[t4], acc[t4], 0, 0, 0);
      }
    }
    if (k0i < 7) {
#pragma unroll
      for (int i = 0; i < 4; i++)
        *(us8*)&sB[buf ^ 1][ccs[i] * 64 + ((segs[i] ^ (ccs[i] & 7)) << 3)] = breg[i];
    }
  }

  // Epilogue: C row = 8*(r>>2) + 4*h + (r&3), col n = n0 + l31; tile = t.
  const float *g, *bb, *mm, *vr;
  unsigned short* So;
  if (p == 0)      { g = gq; bb = bq; mm = mq; vr = vq; So = STq; }
  else if (p == 1) { g = gk; bb = bk; mm = mk; vr = vk; So = STk; }
  else             { g = gv; bb = bv; mm = mv; vr = vv; So = STv; }
  So += (size_t)b * NL * NC;

  int n = n0 + l31;
#pragma unroll
  for (int grp = 0; grp < 4; grp++) {
    int ob = rt * 128 + w * 32 + 8 * grp + 4 * h;
    float av[4], mvv[4], bvv[4];
#pragma unroll
    for (int rr = 0; rr < 4; rr++) {
      av[rr]  = g[ob + rr] / sqrtf(vr[ob + rr] + 1e-5f);
      mvv[rr] = mm[ob + rr];
      bvv[rr] = bb[ob + rr];
    }
    unsigned short sp[4][4];            // [t][rr]
#pragma unroll
    for (int rr = 0; rr < 4; rr++) {
      float vmem = 0.f;
#pragma unroll
      for (int t = 0; t < NT; t++) {
        float y = (acc[t][grp * 4 + rr] - mvv[rr]) * av[rr] + bvv[rr];
        vmem = vmem + (y - vmem) / 1.5f;
        unsigned short s = 0;
        if (vmem - 1.0f >= 0.f) { s = 0x3F80; vmem = 0.f; }
        sp[t][rr] = s;
      }
    }
#pragma unroll
    for (int t = 0; t < NT; t++) {
      us4 pk;
#pragma unroll
      for (int rr = 0; rr < 4; rr++) pk[rr] = sp[t][rr];
      *(us4*)&So[(size_t)(t * NN + n) * NC + ob] = pk;
    }
  }
}

// ---------------------------------------------------------------------------
// Partial Gram: Mpart[ch][bh][e][dd] = sum_{l in 128-chunk} K[l][e]*V[l][dd].
__global__ void k_kvM(const unsigned short* __restrict__ STk,
                      const unsigned short* __restrict__ STv,
                      float* __restrict__ Mpart) {
  int bh = blockIdx.x, ch = blockIdx.y;       // ch 0..7
  int b = bh >> 3, h = bh & 7;
  const unsigned short* Kp = STk + (size_t)b * NL * NC + h * ND;
  const unsigned short* Vp = STv + (size_t)b * NL * NC + h * ND;
  __shared__ float sK[64][72];
  __shared__ float sV[64][72];
  int tid = threadIdx.x, tx = tid & 15, ty = tid >> 4;
  float acc[4][4] = {};
  for (int lt = 0; lt < 2; lt++) {
    int lb = ch * 128 + lt * 64;
#pragma unroll
    for (int i = 0; i < 2; i++) {
      int idx = tid + i * 256;
      int r = idx >> 3, seg = idx & 7;
      us8 kv = *(const us8*)&Kp[(size_t)(lb + r) * NC + seg * 8];
      us8 vv = *(const us8*)&Vp[(size_t)(lb + r) * NC + seg * 8];
#pragma unroll
      for (int q2 = 0; q2 < 8; q2++) {
        sK[r][seg * 8 + q2] = bu2f(kv[q2]);
        sV[r][seg * 8 + q2] = bu2f(vv[q2]);
      }
    }
    __syncthreads();
#pragma unroll 8
    for (int lc = 0; lc < 64; lc++) {
      float kvx[4], vvx[4];
#pragma unroll
      for (int i = 0; i < 4; i++) kvx[i] = sK[lc][ty * 4 + i];
#pragma unroll
      for (int j2 = 0; j2 < 4; j2++) vvx[j2] = sV[lc][tx * 4 + j2];
#pragma unroll
      for (int i = 0; i < 4; i++)
#pragma unroll
        for (int j2 = 0; j2 < 4; j2++)
          acc[i][j2] += kvx[i] * vvx[j2];
    }
    __syncthreads();
  }
  float* Mp = Mpart + ((size_t)ch * 64 + bh) * 4096;
#pragma unroll
  for (int i = 0; i < 4; i++) {
    float4 v4 = make_float4(acc[i][0], acc[i][1], acc[i][2], acc[i][3]);
    *(float4*)&Mp[(ty * 4 + i) * ND + tx * 4] = v4;
  }
}

// ---------------------------------------------------------------------------
// MFMA attention: O^T[dd][l] = sum_e (M1+M2)^T[dd][e] * Q[l][e]; spike O>=12.
__global__ __launch_bounds__(256) void
k_attn(const unsigned short* __restrict__ STq,
       const float* __restrict__ Mpart,
       unsigned short* __restrict__ STs) {
  __shared__ unsigned short MT1[64 * 64];   // [dd][e], 16B chunks phys = c ^ (dd&7)
  __shared__ unsigned short MT2[64 * 64];
  int lt = blockIdx.x, bh = blockIdx.y;
  int b = bh >> 3, h = bh & 7;
  int tid = threadIdx.x;
  int w = tid >> 6, lane = tid & 63, quad = lane >> 4, l15 = lane & 15;

#pragma unroll
  for (int i = 0; i < 4; i++) {
    int idx4 = tid + i * 256;
    float4 s = ((const float4*)Mpart)[(size_t)bh * 1024 + idx4];
#pragma unroll
    for (int ch = 1; ch < 8; ch++) {
      float4 t = ((const float4*)Mpart)[((size_t)ch * 64 + bh) * 1024 + idx4];
      s.x += t.x; s.y += t.y; s.z += t.z; s.w += t.w;
    }
    int e = idx4 >> 4;
    int dd0 = (idx4 * 4) & 63;
    int chunk = e >> 3;
    float sv[4] = {s.x, s.y, s.z, s.w};
#pragma unroll
    for (int r = 0; r < 4; r++) {
      int dd = dd0 + r;
      unsigned short u1 = f2bu(sv[r]);
      unsigned short u2 = f2bu(sv[r] - bu2f(u1));
      int pos = dd * 64 + (((chunk ^ (dd & 7)) << 3) | (e & 7));
      MT1[pos] = u1;
      MT2[pos] = u2;
    }
  }
  __syncthreads();

  const unsigned short* Qp = STq + (size_t)b * NL * NC + h * ND;
  int lbase = lt * 256 + w * 64;

  f32x4 acc[4][4];                           // [ddtile][ltile]
#pragma unroll
  for (int dt = 0; dt < 4; dt++)
#pragma unroll
    for (int j = 0; j < 4; j++) acc[dt][j] = (f32x4){0.f, 0.f, 0.f, 0.f};

#pragma unroll
  for (int ks = 0; ks < 2; ks++) {
    short8v bq[4];
#pragma unroll
    for (int ltile = 0; ltile < 4; ltile++)
      bq[ltile] = *(const short8v*)&Qp[(size_t)(lbase + ltile * 16 + l15) * NC
                                       + ks * 32 + quad * 8];
    int c8 = ks * 4 + quad;
#pragma unroll
    for (int dt = 0; dt < 4; dt++) {
      int dd = dt * 16 + l15;
      int off = dd * 64 + ((c8 ^ (dd & 7)) << 3);
      short8v a1 = *(const short8v*)&MT1[off];
      short8v a2 = *(const short8v*)&MT2[off];
#pragma unroll
      for (int ltile = 0; ltile < 4; ltile++) {
        acc[dt][ltile] = __builtin_amdgcn_mfma_f32_16x16x32_bf16(a1, bq[ltile], acc[dt][ltile], 0, 0, 0);
        acc[dt][ltile] = __builtin_amdgcn_mfma_f32_16x16x32_bf16(a2, bq[ltile], acc[dt][ltile], 0, 0, 0);
      }
    }
  }

  unsigned short* Sp = STs + (size_t)b * NL * NC + h * ND;
#pragma unroll
  for (int dt = 0; dt < 4; dt++)
#pragma unroll
    for (int ltile = 0; ltile < 4; ltile++) {
      int l = lbase + ltile * 16 + l15;
      int dd = dt * 16 + quad * 4;
      us4 pk;
#pragma unroll
      for (int r = 0; r < 4; r++) pk[r] = (acc[dt][ltile][r] >= 12.0f) ? 0x3F80 : 0;
      *(us4*)&Sp[(size_t)l * NC + dd] = pk;
    }
}

// ---------------------------------------------------------------------------
// Final projection: 32x32x16 MFMA. Block tile 128 rows x 64 cols (l); wave w
// owns 32-row strip x 64 cols (2 col-tiles). Same A-direct + B-dbuf structure.
__global__ __launch_bounds__(256) void
k_out(const unsigned short* __restrict__ H3,
      const unsigned short* __restrict__ STs,
      const float* __restrict__ bp, float* __restrict__ out) {
  __shared__ __align__(16) unsigned short sB[2][64 * 64];

  int id = blockIdx.x;                  // 512 = 16 l0 * 4 rt * 8 b
  int l0 = (id & 15) * 64;
  int rt = (id >> 4) & 3;
  int b  = id >> 6;

  int tid = threadIdx.x;
  int w = tid >> 6, lane = tid & 63;
  int l31 = lane & 31, h = lane >> 5;

  const unsigned short* Sb = STs + (size_t)b * NL * NC;

  f32x16 acc[2];
#pragma unroll
  for (int j2 = 0; j2 < 2; j2++)
#pragma unroll
    for (int r = 0; r < 16; r++) acc[j2][r] = 0.f;

  us8 breg[2];
  int ccs[2], segs[2];
  size_t bsrc[2];
#pragma unroll
  for (int i = 0; i < 2; i++) {
    int idx = tid + i * 256;
    int cc = idx >> 3, seg = idx & 7;
    ccs[i] = cc; segs[i] = seg;
    bsrc[i] = (size_t)(l0 + cc) * NC + seg * 8;
  }
#pragma unroll
  for (int i = 0; i < 2; i++) breg[i] = *(const us8*)&Sb[bsrc[i]];
#pragma unroll
  for (int i = 0; i < 2; i++)
    *(us8*)&sB[0][ccs[i] * 64 + ((segs[i] ^ (ccs[i] & 7)) << 3)] = breg[i];

  for (int k0i = 0; k0i < 8; k0i++) {
    __syncthreads();
    int buf = k0i & 1;
    if (k0i < 7) {
#pragma unroll
      for (int i = 0; i < 2; i++)
        breg[i] = *(const us8*)&Sb[bsrc[i] + (size_t)(k0i + 1) * 64];
    }
#pragma unroll
    for (int kstep = 0; kstep < 4; kstep++) {
      int c8 = kstep * 2 + h;
      short8v bf[2];
#pragma unroll
      for (int j2 = 0; j2 < 2; j2++) {
        int cc = j2 * 32 + l31;
        bf[j2] = *(const short8v*)&sB[buf][cc * 64 + ((c8 ^ (cc & 7)) << 3)];
      }
#pragma unroll
      for (int j = 0; j < 3; j++) {
        const unsigned short* Hj =
            H3 + ((size_t)((((9 + j) * 16 + rt * 4 + w) * 8 + k0i) * 4 + kstep)) * 512;
        short8v a = *(const short8v*)&Hj[lane * 8];
#pragma unroll
        for (int j2 = 0; j2 < 2; j2++)
          acc[j2] = __builtin_amdgcn_mfma_f32_32x32x16_bf16(a, bf[j2], acc[j2], 0, 0, 0);
      }
    }
    if (k0i < 7) {
#pragma unroll
      for (int i = 0; i < 2; i++)
        *(us8*)&sB[buf ^ 1][ccs[i] * 64 + ((segs[i] ^ (ccs[i] & 7)) << 3)] = breg[i];
    }
  }

#pragma unroll
  for (int grp = 0; grp < 4; grp++) {
    int ob = rt * 128 + w * 32 + 8 * grp + 4 * h;
#pragma unroll
    for (int j2 = 0; j2 < 2; j2++) {
      int l = l0 + j2 * 32 + l31;
#pragma unroll
      for (int rr = 0; rr < 4; rr++)
        out[((size_t)(b * NC + ob + rr)) * NL + l] = acc[j2][grp * 4 + rr] + bp[ob + rr];
    }
  }
}

// ---------------------------------------------------------------------------
extern "C" void kernel_launch(void* const* d_in, const int* in_sizes, int n_in,
                              void* d_out, int out_size, void* d_ws, size_t ws_size,
                              hipStream_t stream) {
  (void)in_sizes; (void)n_in; (void)out_size; (void)ws_size;
  const float* x   = (const float*)d_in[0];
  const float* wq  = (const float*)d_in[1];
  const float* wk  = (const float*)d_in[2];
  const float* wv  = (const float*)d_in[3];
  const float* wp  = (const float*)d_in[4];
  const float* bp  = (const float*)d_in[5];
  const float* gq  = (const float*)d_in[6];
  const float* bq  = (const float*)d_in[7];
  const float* mq  = (const float*)d_in[8];
  const float* vq  = (const float*)d_in[9];
  const float* gk  = (const float*)d_in[10];
  const float* bk  = (const float*)d_in[11];
  const float* mk  = (const float*)d_in[12];
  const float* vk  = (const float*)d_in[13];
  const float* gv  = (const float*)d_in[14];
  const float* bv  = (const float*)d_in[15];
  const float* mv  = (const float*)d_in[16];
  const float* vvv = (const float*)d_in[17];
  const float* gp  = (const float*)d_in[18];
  const float* bpn = (const float*)d_in[19];
  const float* mp  = (const float*)d_in[20];
  const float* vp  = (const float*)d_in[21];

  unsigned short* H3  = (unsigned short*)d_ws;
  unsigned short* ST0 = H3 + (size_t)4 * 3 * NC * NC;
  unsigned short* STq = ST0 + BCL;
  unsigned short* STk = STq + BCL;
  unsigned short* STv = STk + BCL;
  unsigned short* STs = STv + BCL;
  float* Mpart = (float*)(STs + BCL);

  dim3 blk(256);
  k_prep<<<1024, blk, 0, stream>>>(wq, wk, wv, wp, x, gp, bpn, mp, vp, H3, ST0);
  k_qkv<<<768, blk, 0, stream>>>(H3, ST0,
      gq, bq, mq, vq, gk, bk, mk, vk, gv, bv, mv, vvv, STq, STk, STv);
  k_kvM<<<dim3(64, 8), blk, 0, stream>>>(STk, STv, Mpart);
  k_attn<<<dim3(4, 64), blk, 0, stream>>>(STq, Mpart, STs);
  k_out<<<512, blk, 0, stream>>>(H3, STs, bp, (float*)d_out);
}

// Round 10
// 194.277 us; speedup vs baseline: 1.0235x; 1.0166x over previous
//
#include <hip/hip_runtime.h>
#include <hip/hip_bf16.h>

// SpikingSelfAttention — round 10: revert to round-8 16x16 structure; batch
// all A-fragment global loads at the top of each k0 step (latency exposed
// once per k0 instead of 6x). B=8, C=512, T=4, N=256, L=1024, H=8, d=64.
// Exact 3-way bf16 weight split; binary spikes; o = q @ (k^T v) integer-exact.

#define NB 8
#define NC 512
#define NT 4
#define NN 256
#define NL 1024
#define NH 8
#define ND 64
#define BCL (NB*NC*NL)

typedef __attribute__((ext_vector_type(8))) short  short8v;
typedef __attribute__((ext_vector_type(8))) unsigned short us8;
typedef __attribute__((ext_vector_type(4))) unsigned short us4;
typedef __attribute__((ext_vector_type(4))) float f32x4;

__device__ __forceinline__ float bu2f(unsigned short u) {
  return __uint_as_float(((unsigned)u) << 16);
}
__device__ __forceinline__ unsigned short f2bu(float f) {   // RNE f32->bf16
  unsigned b = __float_as_uint(f);
  return (unsigned short)((b + 0x7FFFu + ((b >> 16) & 1u)) >> 16);
}

// ---------------------------------------------------------------------------
// k_prep: blocks [0,512) = weight split into fragment-ordered H2;
//         blocks [512,1024) = proj BN+LIF -> ST0[b][l][c] bf16.
// H2 layout: offset = ((((p*3+j)*4+rt)*8+k0i)*8+chunk)*1024 + r*8
__global__ void k_prep(const float* __restrict__ wq, const float* __restrict__ wk,
                       const float* __restrict__ wv, const float* __restrict__ wp,
                       const float* __restrict__ x,
                       const float* __restrict__ g,  const float* __restrict__ bt,
                       const float* __restrict__ mu, const float* __restrict__ var,
                       unsigned short* __restrict__ H2,
                       unsigned short* __restrict__ ST0) {
  if (blockIdx.x < 512) {
    int gi = blockIdx.x * 256 + threadIdx.x;       // (p,o,k8): 4*512*64
    int p = gi >> 15;
    int o = (gi >> 6) & 511;
    int k8 = gi & 63;
    int rt = o >> 7, r = o & 127;
    int k0i = k8 >> 3, chunk = k8 & 7;
    const float* W = (p == 0) ? wq : (p == 1) ? wk : (p == 2) ? wv : wp;
    const float* src = W + (size_t)o * NC + k8 * 8;
    us8 a[3];
#pragma unroll
    for (int i = 0; i < 8; i++) {
      float w = src[i];
      unsigned short u1 = f2bu(w);
      float r1 = w - bu2f(u1);
      unsigned short u2 = f2bu(r1);
      float r2 = r1 - bu2f(u2);
      unsigned short u3 = f2bu(r2);
      a[0][i] = u1; a[1][i] = u2; a[2][i] = u3;
    }
#pragma unroll
    for (int j = 0; j < 3; j++) {
      size_t off = ((size_t)((((p * 3 + j) * 4 + rt) * 8 + k0i) * 8 + chunk)) * 1024
                   + (size_t)r * 8;
      *(us8*)&H2[off] = a[j];
    }
  } else {
    int bidx = blockIdx.x - 512;
    int b  = bidx >> 6;
    int c0 = (bidx & 63) * 8;
    int n  = threadIdx.x;
    unsigned short spk[NT][8];
#pragma unroll
    for (int i = 0; i < 8; i++) {
      int c = c0 + i;
      float inv = g[c] / sqrtf(var[c] + 1e-5f);
      float m = mu[c], be = bt[c];
      const float* xp = x + ((size_t)(b * NC + c)) * NL + n;
      float v = 0.f;
#pragma unroll
      for (int t = 0; t < NT; t++) {
        float y = (xp[t * NN] - m) * inv + be;
        v = v + (y - v) / 1.5f;
        unsigned short s = 0;
        if (v - 1.0f >= 0.f) { s = 0x3F80; v = 0.f; }
        spk[t][i] = s;
      }
    }
#pragma unroll
    for (int t = 0; t < NT; t++) {
      us8 pk;
#pragma unroll
      for (int i = 0; i < 8; i++) pk[i] = spk[t][i];
      *(us8*)&ST0[((size_t)b * NL + t * NN + n) * NC + c0] = pk;
    }
  }
}

// ---------------------------------------------------------------------------
// Fused q/k/v projection + BN + LIF. 16x16x32 MFMA, 128x128 tile, 4x1 wave
// strips (32 rows x 128 cols). Per k0: ALL 12 A-frag loads batched up front
// (one latency exposure), B frags read once from LDS and reused over 3 planes.
__global__ __launch_bounds__(256) void
k_qkv(const unsigned short* __restrict__ H2,
      const unsigned short* __restrict__ ST0,
      const float* __restrict__ gq, const float* __restrict__ bq,
      const float* __restrict__ mq, const float* __restrict__ vq,
      const float* __restrict__ gk, const float* __restrict__ bk,
      const float* __restrict__ mk, const float* __restrict__ vk,
      const float* __restrict__ gv, const float* __restrict__ bv,
      const float* __restrict__ mv, const float* __restrict__ vv,
      unsigned short* __restrict__ STq, unsigned short* __restrict__ STk,
      unsigned short* __restrict__ STv) {
  __shared__ __align__(16) unsigned short sB[2][128 * 64];

  int id = blockIdx.x;                  // 768 = 8 n0 * 4 rt * 8 b * 3 p
  int n0 = (id & 7) * 32;
  int rt = (id >> 3) & 3;
  int b  = (id >> 5) & 7;
  int p  = id >> 8;

  int tid = threadIdx.x;
  int w = tid >> 6, lane = tid & 63, quad = lane >> 4, l15 = lane & 15;
  int xorv = l15 & 7;

  const unsigned short* Sb = ST0 + (size_t)b * NL * NC;
  // Base pointer for this block's A fragments (plane j adds j*8192*... below).
  const unsigned short* Hbase = H2 + ((size_t)((p * 3) * 4 + rt) * 8) * 8192;

  f32x4 acc[2][8];
#pragma unroll
  for (int ri = 0; ri < 2; ri++)
#pragma unroll
    for (int jj = 0; jj < 8; jj++) acc[ri][jj] = (f32x4){0.f, 0.f, 0.f, 0.f};

  us8 breg[4];
  int ccs[4], segs[4];
  size_t bsrc[4];
#pragma unroll
  for (int i = 0; i < 4; i++) {
    int idx = tid + i * 256;
    int cc = idx >> 3, seg = idx & 7;
    int t = (cc >> 4) & 3, nn = (cc & 15) | ((cc >> 6) << 4);
    ccs[i] = cc; segs[i] = seg;
    bsrc[i] = (size_t)(t * NN + n0 + nn) * NC + seg * 8;
  }
#pragma unroll
  for (int i = 0; i < 4; i++) breg[i] = *(const us8*)&Sb[bsrc[i]];      // k0=0
#pragma unroll
  for (int i = 0; i < 4; i++)
    *(us8*)&sB[0][ccs[i] * 64 + ((segs[i] ^ (ccs[i] & 7)) << 3)] = breg[i];

  for (int k0i = 0; k0i < 8; k0i++) {
    __syncthreads();
    int buf = k0i & 1;

    // Batch ALL A-fragment loads for this k0 (12 independent dwordx4).
    short8v Ar[2][3][2];                // [ks][plane][row-half]
#pragma unroll
    for (int ks = 0; ks < 2; ks++) {
      int c8 = ks * 4 + quad;
#pragma unroll
      for (int j = 0; j < 3; j++) {
        const unsigned short* Hj =
            Hbase + ((size_t)j * 4 * 8 + k0i) * 8192 + (size_t)c8 * 1024;
        Ar[ks][j][0] = *(const short8v*)&Hj[(w * 32 + l15) * 8];
        Ar[ks][j][1] = *(const short8v*)&Hj[(w * 32 + 16 + l15) * 8];
      }
    }
    if (k0i < 7) {
#pragma unroll
      for (int i = 0; i < 4; i++)
        breg[i] = *(const us8*)&Sb[bsrc[i] + (size_t)(k0i + 1) * 64];
    }
#pragma unroll
    for (int ks = 0; ks < 2; ks++) {
      int c8 = ks * 4 + quad;
      int poff = (c8 ^ xorv) << 3;
      short8v bf[8];
#pragma unroll
      for (int jj = 0; jj < 8; jj++)
        bf[jj] = *(const short8v*)&sB[buf][(jj * 16 + l15) * 64 + poff];
#pragma unroll
      for (int j = 0; j < 3; j++) {
#pragma unroll
        for (int jj = 0; jj < 8; jj++) {
          acc[0][jj] = __builtin_amdgcn_mfma_f32_16x16x32_bf16(Ar[ks][j][0], bf[jj], acc[0][jj], 0, 0, 0);
          acc[1][jj] = __builtin_amdgcn_mfma_f32_16x16x32_bf16(Ar[ks][j][1], bf[jj], acc[1][jj], 0, 0, 0);
        }
      }
    }
    if (k0i < 7) {
#pragma unroll
      for (int i = 0; i < 4; i++)
        *(us8*)&sB[buf ^ 1][ccs[i] * 64 + ((segs[i] ^ (ccs[i] & 7)) << 3)] = breg[i];
    }
  }

  const float *g, *bb, *mm, *vr;
  unsigned short* So;
  if (p == 0)      { g = gq; bb = bq; mm = mq; vr = vq; So = STq; }
  else if (p == 1) { g = gk; bb = bk; mm = mk; vr = vk; So = STk; }
  else             { g = gv; bb = bv; mm = mv; vr = vv; So = STv; }
  So += (size_t)b * NL * NC;

#pragma unroll
  for (int ri = 0; ri < 2; ri++) {
    int ob = rt * 128 + w * 32 + ri * 16 + quad * 4;
    float av[4], mvv[4], bvv[4];
#pragma unroll
    for (int r = 0; r < 4; r++) {
      av[r]  = g[ob + r] / sqrtf(vr[ob + r] + 1e-5f);
      mvv[r] = mm[ob + r];
      bvv[r] = bb[ob + r];
    }
#pragma unroll
    for (int nh = 0; nh < 2; nh++) {
      int n = n0 + (nh << 4) + l15;
      unsigned short sp[4][4];          // [t][r]
#pragma unroll
      for (int r = 0; r < 4; r++) {
        float vmem = 0.f;
#pragma unroll
        for (int t = 0; t < NT; t++) {
          float y = (acc[ri][nh * 4 + t][r] - mvv[r]) * av[r] + bvv[r];
          vmem = vmem + (y - vmem) / 1.5f;
          unsigned short s = 0;
          if (vmem - 1.0f >= 0.f) { s = 0x3F80; vmem = 0.f; }
          sp[t][r] = s;
        }
      }
#pragma unroll
      for (int t = 0; t < NT; t++) {
        us4 pk;
#pragma unroll
        for (int r = 0; r < 4; r++) pk[r] = sp[t][r];
        *(us4*)&So[(size_t)(t * NN + n) * NC + ob] = pk;
      }
    }
  }
}

// ---------------------------------------------------------------------------
// Partial Gram: Mpart[ch][bh][e][dd] = sum_{l in 128-chunk} K[l][e]*V[l][dd].
__global__ void k_kvM(const unsigned short* __restrict__ STk,
                      const unsigned short* __restrict__ STv,
                      float* __restrict__ Mpart) {
  int bh = blockIdx.x, ch = blockIdx.y;       // ch 0..7
  int b = bh >> 3, h = bh & 7;
  const unsigned short* Kp = STk + (size_t)b * NL * NC + h * ND;
  const unsigned short* Vp = STv + (size_t)b * NL * NC + h * ND;
  __shared__ float sK[64][72];
  __shared__ float sV[64][72];
  int tid = threadIdx.x, tx = tid & 15, ty = tid >> 4;
  float acc[4][4] = {};
  for (int lt = 0; lt < 2; lt++) {
    int lb = ch * 128 + lt * 64;
#pragma unroll
    for (int i = 0; i < 2; i++) {
      int idx = tid + i * 256;
      int r = idx >> 3, seg = idx & 7;
      us8 kv = *(const us8*)&Kp[(size_t)(lb + r) * NC + seg * 8];
      us8 vv = *(const us8*)&Vp[(size_t)(lb + r) * NC + seg * 8];
#pragma unroll
      for (int q2 = 0; q2 < 8; q2++) {
        sK[r][seg * 8 + q2] = bu2f(kv[q2]);
        sV[r][seg * 8 + q2] = bu2f(vv[q2]);
      }
    }
    __syncthreads();
#pragma unroll 8
    for (int lc = 0; lc < 64; lc++) {
      float kvx[4], vvx[4];
#pragma unroll
      for (int i = 0; i < 4; i++) kvx[i] = sK[lc][ty * 4 + i];
#pragma unroll
      for (int j2 = 0; j2 < 4; j2++) vvx[j2] = sV[lc][tx * 4 + j2];
#pragma unroll
      for (int i = 0; i < 4; i++)
#pragma unroll
        for (int j2 = 0; j2 < 4; j2++)
          acc[i][j2] += kvx[i] * vvx[j2];
    }
    __syncthreads();
  }
  float* Mp = Mpart + ((size_t)ch * 64 + bh) * 4096;
#pragma unroll
  for (int i = 0; i < 4; i++) {
    float4 v4 = make_float4(acc[i][0], acc[i][1], acc[i][2], acc[i][3]);
    *(float4*)&Mp[(ty * 4 + i) * ND + tx * 4] = v4;
  }
}

// ---------------------------------------------------------------------------
// MFMA attention: O^T[dd][l] = sum_e (M1+M2)^T[dd][e] * Q[l][e]; spike O>=12.
// M split into two exact bf16 planes (M integer <=1024 — split exact).
__global__ __launch_bounds__(256) void
k_attn(const unsigned short* __restrict__ STq,
       const float* __restrict__ Mpart,
       unsigned short* __restrict__ STs) {
  __shared__ unsigned short MT1[64 * 64];   // [dd][e], 16B chunks phys = c ^ (dd&7)
  __shared__ unsigned short MT2[64 * 64];
  int lt = blockIdx.x, bh = blockIdx.y;
  int b = bh >> 3, h = bh & 7;
  int tid = threadIdx.x;
  int w = tid >> 6, lane = tid & 63, quad = lane >> 4, l15 = lane & 15;

#pragma unroll
  for (int i = 0; i < 4; i++) {
    int idx4 = tid + i * 256;
    float4 s = ((const float4*)Mpart)[(size_t)bh * 1024 + idx4];
#pragma unroll
    for (int ch = 1; ch < 8; ch++) {
      float4 t = ((const float4*)Mpart)[((size_t)ch * 64 + bh) * 1024 + idx4];
      s.x += t.x; s.y += t.y; s.z += t.z; s.w += t.w;
    }
    int e = idx4 >> 4;
    int dd0 = (idx4 * 4) & 63;
    int chunk = e >> 3;
    float sv[4] = {s.x, s.y, s.z, s.w};
#pragma unroll
    for (int r = 0; r < 4; r++) {
      int dd = dd0 + r;
      unsigned short u1 = f2bu(sv[r]);
      unsigned short u2 = f2bu(sv[r] - bu2f(u1));
      int pos = dd * 64 + (((chunk ^ (dd & 7)) << 3) | (e & 7));
      MT1[pos] = u1;
      MT2[pos] = u2;
    }
  }
  __syncthreads();

  const unsigned short* Qp = STq + (size_t)b * NL * NC + h * ND;
  int lbase = lt * 256 + w * 64;

  f32x4 acc[4][4];                           // [ddtile][ltile]
#pragma unroll
  for (int dt = 0; dt < 4; dt++)
#pragma unroll
    for (int j = 0; j < 4; j++) acc[dt][j] = (f32x4){0.f, 0.f, 0.f, 0.f};

#pragma unroll
  for (int ks = 0; ks < 2; ks++) {
    short8v bq[4];
#pragma unroll
    for (int ltile = 0; ltile < 4; ltile++)
      bq[ltile] = *(const short8v*)&Qp[(size_t)(lbase + ltile * 16 + l15) * NC
                                       + ks * 32 + quad * 8];
    int c8 = ks * 4 + quad;
#pragma unroll
    for (int dt = 0; dt < 4; dt++) {
      int dd = dt * 16 + l15;
      int off = dd * 64 + ((c8 ^ (dd & 7)) << 3);
      short8v a1 = *(const short8v*)&MT1[off];
      short8v a2 = *(const short8v*)&MT2[off];
#pragma unroll
      for (int ltile = 0; ltile < 4; ltile++) {
        acc[dt][ltile] = __builtin_amdgcn_mfma_f32_16x16x32_bf16(a1, bq[ltile], acc[dt][ltile], 0, 0, 0);
        acc[dt][ltile] = __builtin_amdgcn_mfma_f32_16x16x32_bf16(a2, bq[ltile], acc[dt][ltile], 0, 0, 0);
      }
    }
  }

  unsigned short* Sp = STs + (size_t)b * NL * NC + h * ND;
#pragma unroll
  for (int dt = 0; dt < 4; dt++)
#pragma unroll
    for (int ltile = 0; ltile < 4; ltile++) {
      int l = lbase + ltile * 16 + l15;
      int dd = dt * 16 + quad * 4;
      us4 pk;
#pragma unroll
      for (int r = 0; r < 4; r++) pk[r] = (acc[dt][ltile][r] >= 12.0f) ? 0x3F80 : 0;
      *(us4*)&Sp[(size_t)l * NC + dd] = pk;
    }
}

// ---------------------------------------------------------------------------
// Final projection: 16x16x32, 128 rows x 64 cols, batched A-loads per k0.
__global__ __launch_bounds__(256) void
k_out(const unsigned short* __restrict__ H2,
      const unsigned short* __restrict__ STs,
      const float* __restrict__ bp, float* __restrict__ out) {
  __shared__ __align__(16) unsigned short sB[2][64 * 64];

  int id = blockIdx.x;                  // 512 = 16 l0 * 4 rt * 8 b
  int l0 = (id & 15) * 64;
  int rt = (id >> 4) & 3;
  int b  = id >> 6;

  int tid = threadIdx.x;
  int w = tid >> 6, lane = tid & 63, quad = lane >> 4, l15 = lane & 15;
  int xorv = l15 & 7;

  const unsigned short* Sb = STs + (size_t)b * NL * NC;
  const unsigned short* Hbase = H2 + ((size_t)(9 * 4 + rt) * 8) * 8192;  // p=3

  f32x4 acc[2][4];
#pragma unroll
  for (int ri = 0; ri < 2; ri++)
#pragma unroll
    for (int jj = 0; jj < 4; jj++) acc[ri][jj] = (f32x4){0.f, 0.f, 0.f, 0.f};

  us8 breg[2];
  int ccs[2], segs[2];
  size_t bsrc[2];
#pragma unroll
  for (int i = 0; i < 2; i++) {
    int idx = tid + i * 256;
    int cc = idx >> 3, seg = idx & 7;
    ccs[i] = cc; segs[i] = seg;
    bsrc[i] = (size_t)(l0 + cc) * NC + seg * 8;
  }
#pragma unroll
  for (int i = 0; i < 2; i++) breg[i] = *(const us8*)&Sb[bsrc[i]];
#pragma unroll
  for (int i = 0; i < 2; i++)
    *(us8*)&sB[0][ccs[i] * 64 + ((segs[i] ^ (ccs[i] & 7)) << 3)] = breg[i];

  for (int k0i = 0; k0i < 8; k0i++) {
    __syncthreads();
    int buf = k0i & 1;

    short8v Ar[2][3][2];
#pragma unroll
    for (int ks = 0; ks < 2; ks++) {
      int c8 = ks * 4 + quad;
#pragma unroll
      for (int j = 0; j < 3; j++) {
        const unsigned short* Hj =
            Hbase + ((size_t)j * 4 * 8 + k0i) * 8192 + (size_t)c8 * 1024;
        Ar[ks][j][0] = *(const short8v*)&Hj[(w * 32 + l15) * 8];
        Ar[ks][j][1] = *(const short8v*)&Hj[(w * 32 + 16 + l15) * 8];
      }
    }
    if (k0i < 7) {
#pragma unroll
      for (int i = 0; i < 2; i++)
        breg[i] = *(const us8*)&Sb[bsrc[i] + (size_t)(k0i + 1) * 64];
    }
#pragma unroll
    for (int ks = 0; ks < 2; ks++) {
      int c8 = ks * 4 + quad;
      int poff = (c8 ^ xorv) << 3;
      short8v bf[4];
#pragma unroll
      for (int jj = 0; jj < 4; jj++)
        bf[jj] = *(const short8v*)&sB[buf][(jj * 16 + l15) * 64 + poff];
#pragma unroll
      for (int j = 0; j < 3; j++) {
#pragma unroll
        for (int jj = 0; jj < 4; jj++) {
          acc[0][jj] = __builtin_amdgcn_mfma_f32_16x16x32_bf16(Ar[ks][j][0], bf[jj], acc[0][jj], 0, 0, 0);
          acc[1][jj] = __builtin_amdgcn_mfma_f32_16x16x32_bf16(Ar[ks][j][1], bf[jj], acc[1][jj], 0, 0, 0);
        }
      }
    }
    if (k0i < 7) {
#pragma unroll
      for (int i = 0; i < 2; i++)
        *(us8*)&sB[buf ^ 1][ccs[i] * 64 + ((segs[i] ^ (ccs[i] & 7)) << 3)] = breg[i];
    }
  }

#pragma unroll
  for (int ri = 0; ri < 2; ri++) {
    int ob = rt * 128 + w * 32 + ri * 16 + quad * 4;
#pragma unroll
    for (int jj = 0; jj < 4; jj++) {
      int l = l0 + jj * 16 + l15;
#pragma unroll
      for (int r = 0; r < 4; r++)
        out[((size_t)(b * NC + ob + r)) * NL + l] = acc[ri][jj][r] + bp[ob + r];
    }
  }
}

// ---------------------------------------------------------------------------
extern "C" void kernel_launch(void* const* d_in, const int* in_sizes, int n_in,
                              void* d_out, int out_size, void* d_ws, size_t ws_size,
                              hipStream_t stream) {
  (void)in_sizes; (void)n_in; (void)out_size; (void)ws_size;
  const float* x   = (const float*)d_in[0];
  const float* wq  = (const float*)d_in[1];
  const float* wk  = (const float*)d_in[2];
  const float* wv  = (const float*)d_in[3];
  const float* wp  = (const float*)d_in[4];
  const float* bp  = (const float*)d_in[5];
  const float* gq  = (const float*)d_in[6];
  const float* bq  = (const float*)d_in[7];
  const float* mq  = (const float*)d_in[8];
  const float* vq  = (const float*)d_in[9];
  const float* gk  = (const float*)d_in[10];
  const float* bk  = (const float*)d_in[11];
  const float* mk  = (const float*)d_in[12];
  const float* vk  = (const float*)d_in[13];
  const float* gv  = (const float*)d_in[14];
  const float* bv  = (const float*)d_in[15];
  const float* mv  = (const float*)d_in[16];
  const float* vvv = (const float*)d_in[17];
  const float* gp  = (const float*)d_in[18];
  const float* bpn = (const float*)d_in[19];
  const float* mp  = (const float*)d_in[20];
  const float* vp  = (const float*)d_in[21];

  unsigned short* H2  = (unsigned short*)d_ws;
  unsigned short* ST0 = H2 + (size_t)4 * 3 * NC * NC;
  unsigned short* STq = ST0 + BCL;
  unsigned short* STk = STq + BCL;
  unsigned short* STv = STk + BCL;
  unsigned short* STs = STv + BCL;
  float* Mpart = (float*)(STs + BCL);

  dim3 blk(256);
  k_prep<<<1024, blk, 0, stream>>>(wq, wk, wv, wp, x, gp, bpn, mp, vp, H2, ST0);
  k_qkv<<<768, blk, 0, stream>>>(H2, ST0,
      gq, bq, mq, vq, gk, bk, mk, vk, gv, bv, mv, vvv, STq, STk, STv);
  k_kvM<<<dim3(64, 8), blk, 0, stream>>>(STk, STv, Mpart);
  k_attn<<<dim3(4, 64), blk, 0, stream>>>(STq, Mpart, STs);
  k_out<<<512, blk, 0, stream>>>(H2, STs, bp, (float*)d_out);
}